// Round 1
// baseline (149.489 us; speedup 1.0000x reference)
//
#include <hip/hip_runtime.h>

#define NTY 50
#define NCA 20
#define ED  64
#define NB  4
#define SL  256

#define TYPE_BLOCKS (NB * NTY)   // 200: one per (batch, target type)
#define CAT_BLOCKS  (NB * NCA)   // 80:  one per (batch, target category)
#define MAIN_BLOCKS (TYPE_BLOCKS + CAT_BLOCKS)

// ws float layout — every slot has exactly ONE writer, so no zero-init needed:
//   ws_m [NB][SL]  @ WS_M  : per-event type-channel partial (events i>=1)
//   ws_n [NB][SL]  @ WS_N  : per-event cat-channel partial  (events i>=1)
//   ws_it[NB][NTY] @ WS_IT : horizon type partial per (b,t)
//   ws_nT[NB][ED]  @ WS_NT : horizon cat n-vector per b
#define WS_M  0
#define WS_N  (NB * SL)
#define WS_IT (2 * NB * SL)
#define WS_NT (2 * NB * SL + NB * NTY)

__device__ __forceinline__ float softplusf(float x) {
    return (x > 0.f) ? x + log1pf(__expf(-x)) : log1pf(__expf(x));
}

__device__ __forceinline__ float waveReduceSum(float v) {
    #pragma unroll
    for (int off = 32; off > 0; off >>= 1) v += __shfl_down(v, off, 64);
    return v;
}

// Hawkes prefix factorization: exp(-R*(tau - t_s)) = exp(-R*tau) * exp(R*t_s),
// R = tr*P[k,tgt]*f[k] per lane(e). W[k][e] = sum_{s processed} exp(R*t_s) lives
// in LDS; events of this block's target query it with a 50/20-term epilogue.
__global__ __launch_bounds__(256) void hawkes_main(
        const float* __restrict__ times,
        const int*   __restrict__ types,
        const int*   __restrict__ cats,
        const int*   __restrict__ Tp,
        const float* __restrict__ type_emb,
        const float* __restrict__ cat_emb,
        const float* __restrict__ amat,
        const float* __restrict__ bmat,
        const float* __restrict__ A,
        const float* __restrict__ P,
        const float* __restrict__ Bm,
        const float* __restrict__ Q,
        float* __restrict__ ws) {
    const int blk  = blockIdx.x;
    const int tid  = threadIdx.x;
    const int lane = tid & 63;
    const int w    = tid >> 6;

    const bool isType = blk < TYPE_BLOCKS;
    const int  b   = isType ? blk / NTY : (blk - TYPE_BLOCKS) / NCA;
    const int  tgt = isType ? blk % NTY : (blk - TYPE_BLOCKS) % NCA;
    const int  NK  = isType ? NTY : NCA;
    const int  base = b * SL;

    __shared__ float Wk[NTY * ED];     // running exp-sums (cat uses first 20 rows)
    __shared__ float Rk[NTY * ED];     // decay rates
    __shared__ float Ck[NTY * ED];     // tr*A*f (or tr*Bm*g) coefficients
    __shared__ float times_sh[SL + 1]; // [SL] holds horizon T (virtual event)
    __shared__ int   types_sh[SL];
    __shared__ int   cats_sh[SL];
    __shared__ float qp[4][ED];
    __shared__ int   evl[SL];
    __shared__ int   evcnt;

    // ---- stage sequences ----
    times_sh[tid] = times[base + tid];
    types_sh[tid] = types[base + tid];
    cats_sh[tid]  = cats[base + tid];
    if (tid == 0) times_sh[SL] = (float)Tp[0];
    __syncthreads();

    const float tr   = isType ? type_emb[tgt * ED + lane] : cat_emb[tgt * ED + lane];
    const float areg = isType ? amat[tgt * ED + lane] : 0.f;

    // ---- stage per-k coefficient rows (the ONLY bulk global traffic) ----
    for (int k = w; k < NK; k += 4) {
        float f, Cv, Pv;
        if (isType) {
            f  = type_emb[k * ED + lane];
            Cv = A[(k * NTY + tgt) * ED + lane];
            Pv = P[(k * NTY + tgt) * ED + lane];
        } else {
            f  = cat_emb[k * ED + lane];
            Cv = Bm[(k * NCA + tgt) * ED + lane];
            Pv = Q [(k * NCA + tgt) * ED + lane];
        }
        Ck[k * ED + lane] = tr * Cv * f;
        Rk[k * ED + lane] = tr * Pv * f;
        Wk[k * ED + lane] = 0.f;
    }

    // ---- wave 0: ordered compaction of this block's event positions ----
    if (w == 0) {
        int run = 0;
        #pragma unroll
        for (int jj = 0; jj < 4; ++jj) {
            const int p = lane + 64 * jj;
            const bool pred = (p >= 1) && (isType ? (types_sh[p] == tgt)
                                                  : (cats_sh[p - 1] == tgt));
            const unsigned long long mk = __ballot(pred);
            if (pred) evl[run + __popcll(mk & ((1ull << lane) - 1ull))] = p;
            run += __popcll(mk);
        }
        if (lane == 0) evcnt = run;
    }
    __syncthreads();

    const int ne = evcnt;
    int prev = 0;
    for (int j = 0; j <= ne; ++j) {
        const int ie = (j < ne) ? evl[j] : SL;   // ie==SL -> virtual horizon event

        // prefetch the event's extra row early so latency hides under updates
        float evrow = 0.f;
        if (w == 0 && j < ne) {
            evrow = isType ? bmat[cats_sh[ie - 1] * ED + lane]
                           : type_emb[types_sh[ie] * ED + lane];
        }

        // ---- W updates for sources in [prev, ie), split across waves ----
        #pragma unroll 4
        for (int s = prev + w; s < ie; s += 4) {
            const int k = isType ? types_sh[s] : cats_sh[s];
            atomicAdd(&Wk[k * ED + lane], __expf(Rk[k * ED + lane] * times_sh[s]));
        }
        __syncthreads();

        // ---- query at tau: k-space split across waves ----
        const float tau = times_sh[ie];
        float q = 0.f;
        for (int k = w; k < NK; k += 4)
            q += Ck[k * ED + lane] * __expf(-Rk[k * ED + lane] * tau) * Wk[k * ED + lane];
        qp[w][lane] = q;
        __syncthreads();

        if (w == 0) {
            const float qs = qp[0][lane] + qp[1][lane] + qp[2][lane] + qp[3][lane];
            if (isType) {
                if (j < ne) {
                    // lambda type part: sum_e te*(a + b[c_i]) + m[t_i,e]
                    const float v = waveReduceSum(qs + tr * (areg + evrow));
                    if (lane == 0) ws[WS_M + b * SL + ie] = v;
                } else {
                    // horizon: sum_e te*a + m_T[t,e]
                    const float v = waveReduceSum(qs + tr * areg);
                    if (lane == 0) ws[WS_IT + b * NTY + tgt] = v;
                }
            } else {
                if (j < ne) {
                    // lambda cat part: sum_e te[t_i,e] * n[c_i,e]
                    const float v = waveReduceSum(qs * evrow);
                    if (lane == 0) ws[WS_N + b * SL + ie] = v;
                } else if (tgt == cats_sh[SL - 1]) {
                    // horizon n-vector for last_cat (per-lane store, no reduce)
                    ws[WS_NT + b * ED + lane] = qs;
                }
            }
        }
        __syncthreads();   // W reads done before next chunk's updates
        prev = ie;
    }
}

__global__ __launch_bounds__(256) void hawkes_final(
        const float* __restrict__ times,
        const int*   __restrict__ types,
        const int*   __restrict__ cats,
        const int*   __restrict__ Tp,
        const float* __restrict__ type_emb,
        const float* __restrict__ amat,
        const float* __restrict__ bmat,
        const float* __restrict__ ws,
        float* __restrict__ out) {
    const int tid  = threadIdx.x;
    const int lane = tid & 63;
    const int w    = tid >> 6;          // wave w also owns batch w

    __shared__ float tsl[4][ED];
    __shared__ float wred[4], i0red[4], intb[4];

    const float Tf = (float)Tp[0];

    // ---- log-likelihood over events i>=1 (thread tid -> i=tid+1, all batches) ----
    float llp = 0.f;
    const int i = tid + 1;
    if (i < SL) {
        #pragma unroll
        for (int bb = 0; bb < NB; ++bb) {
            const float lam = ws[WS_M + bb * SL + i] + ws[WS_N + bb * SL + i];
            llp += logf(lam + 1e-16f) + lam;
        }
    }

    // ---- empty-history lambda_0 for batch w ----
    const int t0 = types[w * SL];
    const float v0 = softplusf(type_emb[t0 * ED + lane] * amat[t0 * ED + lane]);

    // ---- TS[e] = sum_t te[t,e] and I0 = sum softplus(te*a), t split by wave ----
    float tsp = 0.f, i0p = 0.f;
    for (int t = w; t < NTY; t += 4) {
        const float tv = type_emb[t * ED + lane];
        tsp += tv;
        i0p += softplusf(tv * amat[t * ED + lane]);
    }
    tsl[w][lane] = tsp;

    const float lam0 = waveReduceSum(v0);
    const float wll  = waveReduceSum(llp);
    const float wi0  = waveReduceSum(i0p);
    if (lane == 0) {
        wred[w]  = wll + logf(lam0 + 1e-16f) + lam0;
        i0red[w] = wi0;
    }
    __syncthreads();

    // ---- horizon integral for batch w ----
    const float TS_l = tsl[0][lane] + tsl[1][lane] + tsl[2][lane] + tsl[3][lane];
    const int   lc   = cats[w * SL + SL - 1];
    const float bbv  = bmat[lc * ED + lane] + ws[WS_NT + w * ED + lane];
    const float its  = (lane < NTY) ? ws[WS_IT + w * NTY + lane] : 0.f;
    const float ip   = waveReduceSum(its + bbv * TS_l);
    if (lane == 0) intb[w] = ip * (Tf - times[w * SL + SL - 1]);
    __syncthreads();

    if (tid == 0) {
        const float ll = wred[0] + wred[1] + wred[2] + wred[3];
        const float I0 = i0red[0] + i0red[1] + i0red[2] + i0red[3];
        const float t0s = times[0] + times[SL] + times[2 * SL] + times[3 * SL];
        const float tot = intb[0] + intb[1] + intb[2] + intb[3] + I0 * t0s;
        out[0] = -(ll - tot);
    }
}

extern "C" void kernel_launch(void* const* d_in, const int* in_sizes, int n_in,
                              void* d_out, int out_size, void* d_ws, size_t ws_size,
                              hipStream_t stream) {
    const float* times    = (const float*)d_in[0];
    const int*   types    = (const int*)  d_in[1];
    const int*   cats     = (const int*)  d_in[2];
    const int*   Tp       = (const int*)  d_in[3];
    const float* type_emb = (const float*)d_in[4];
    const float* cat_emb  = (const float*)d_in[5];
    const float* amat     = (const float*)d_in[6];
    const float* bmat     = (const float*)d_in[7];
    const float* A        = (const float*)d_in[8];
    const float* P        = (const float*)d_in[9];
    const float* Bm       = (const float*)d_in[10];
    const float* Q        = (const float*)d_in[11];
    float* out = (float*)d_out;
    float* ws  = (float*)d_ws;

    // No memset: every ws slot read by hawkes_final is written exactly once by
    // hawkes_main; stream order provides the cross-kernel visibility.
    hawkes_main<<<MAIN_BLOCKS, 256, 0, stream>>>(times, types, cats, Tp,
                                                 type_emb, cat_emb, amat, bmat,
                                                 A, P, Bm, Q, ws);
    hawkes_final<<<1, 256, 0, stream>>>(times, types, cats, Tp,
                                        type_emb, amat, bmat, ws, out);
}

// Round 2
// 119.979 us; speedup vs baseline: 1.2460x; 1.2460x over previous
//
#include <hip/hip_runtime.h>

#define NTY 50
#define NCA 20
#define ED  64
#define NB  4
#define SL  256

#define TYPE_BLOCKS (NB * NTY)   // 200: one per (batch, target type)
#define CAT_BLOCKS  (NB * NCA)   // 80:  one per (batch, target category)
#define MAIN_BLOCKS (TYPE_BLOCKS + CAT_BLOCKS)
#define NTHREADS 512
#define NWAVES   (NTHREADS / 64)
#define JTILE    16

// ws float layout — every slot has exactly ONE writer, no zero-init needed:
#define WS_M  0                        // [NB][SL] per-event type-channel partial
#define WS_N  (NB * SL)                // [NB][SL] per-event cat-channel partial
#define WS_IT (2 * NB * SL)            // [NB][NTY] horizon type partial
#define WS_NT (2 * NB * SL + NB * NTY) // [NB][ED] horizon cat n-vector

__device__ __forceinline__ float softplusf(float x) {
    return (x > 0.f) ? x + log1pf(__expf(-x)) : log1pf(__expf(x));
}

__device__ __forceinline__ float waveReduceSum(float v) {
    #pragma unroll
    for (int off = 32; off > 0; off >>= 1) v += __shfl_down(v, off, 64);
    return v;
}

// Per-thread-register prefix sums: thread owns (k, EPT e-values).
// W[e] = sum_{s<i, key_s==k} exp(R[e]*t_s) lives in VGPRs; the source scan is
// LDS-broadcast reads only — no LDS atomics, no per-event barriers.
template <bool IS_TYPE, int NK, int EPT>
__device__ __forceinline__ void run_channel(
        int b, int tgt, int tid,
        const float* __restrict__ times, const int* __restrict__ types,
        const int* __restrict__ cats, float Tf,
        const float* __restrict__ type_emb, const float* __restrict__ cat_emb,
        const float* __restrict__ amat, const float* __restrict__ bmat,
        const float* __restrict__ Cmat, const float* __restrict__ Pmat,
        float* __restrict__ ws,
        float* times_sh, int* types_sh, int* cats_sh, int* evl, int* evcnt_p,
        float (*qmat)[NTHREADS], float (*nmat)[ED]) {
    const int lane = tid & 63;
    const int w    = tid >> 6;
    constexpr int GPK  = ED / EPT;     // thread-groups per k
    constexpr int NACT = NK * GPK;     // active threads
    const int myk  = tid / GPK;
    const int e0   = (tid % GPK) * EPT;
    const bool active = tid < NACT;
    const int base = b * SL;

    // ---- stage sequences ----
    if (tid < SL) {
        times_sh[tid] = times[base + tid];
        types_sh[tid] = types[base + tid];
        cats_sh[tid]  = cats[base + tid];
    }
    if (tid == 0) times_sh[SL] = Tf;   // virtual horizon event

    // per-lane (lane==e) epilogue registers, type channel only
    float trE = 0.f, aE = 0.f;
    if (IS_TYPE) {
        trE = type_emb[tgt * ED + lane];
        aE  = amat[tgt * ED + lane];
    }

    // ---- per-thread coefficient registers ----
    float Rr[EPT], Cr[EPT], W[EPT];
    if (active) {
        #pragma unroll
        for (int m = 0; m < EPT; ++m) {
            const int e = e0 + m;
            const float tr = IS_TYPE ? type_emb[tgt * ED + e] : cat_emb[tgt * ED + e];
            const float f  = IS_TYPE ? type_emb[myk * ED + e] : cat_emb[myk * ED + e];
            const float Cv = Cmat[(myk * NK + tgt) * ED + e];
            const float Pv = Pmat[(myk * NK + tgt) * ED + e];
            Cr[m] = tr * Cv * f;
            Rr[m] = tr * Pv * f;
            W[m]  = 0.f;
        }
    }
    __syncthreads();

    // ---- wave 0: ordered compaction of this block's event positions ----
    if (w == 0) {
        int run = 0;
        #pragma unroll
        for (int jj = 0; jj < SL / 64; ++jj) {
            const int p = lane + 64 * jj;
            const bool pred = (p >= 1) && (IS_TYPE ? (types_sh[p] == tgt)
                                                   : (cats_sh[p - 1] == tgt));
            const unsigned long long mk = __ballot(pred);
            if (pred) evl[run + __popcll(mk & ((1ull << lane) - 1ull))] = p;
            run += __popcll(mk);
        }
        if (lane == 0) *evcnt_p = run;
    }
    __syncthreads();

    const int ne    = *evcnt_p;
    const int lastc = cats_sh[SL - 1];
    int sp = 0;                         // per-thread source scan pointer

    for (int j0 = 0; j0 <= ne; j0 += JTILE) {
        const int jhi = min(j0 + JTILE - 1, ne);

        // ---- emit: per-thread scan + query, no barriers inside ----
        if (active) {
            for (int j = j0; j <= jhi; ++j) {
                const int ie = (j < ne) ? evl[j] : SL;
                for (; sp < ie; ++sp) {
                    const int ks = IS_TYPE ? types_sh[sp] : cats_sh[sp];
                    if (ks == myk) {
                        const float ts = times_sh[sp];
                        #pragma unroll
                        for (int m = 0; m < EPT; ++m) W[m] += __expf(Rr[m] * ts);
                    }
                }
                const float tau = times_sh[ie];
                if (IS_TYPE || j < ne) {
                    float teRow[EPT];
                    if (!IS_TYPE) {
                        const int tEv = types_sh[ie];
                        #pragma unroll
                        for (int m = 0; m < EPT; ++m)
                            teRow[m] = type_emb[tEv * ED + e0 + m];
                    }
                    float q = 0.f;
                    #pragma unroll
                    for (int m = 0; m < EPT; ++m) {
                        float v = Cr[m] * __expf(-Rr[m] * tau) * W[m];
                        if (!IS_TYPE) v *= teRow[m];
                        q += v;
                    }
                    qmat[j - j0][tid] = q;
                } else {
                    // cat virtual event: keep per-e vector for n_T
                    #pragma unroll
                    for (int m = 0; m < EPT; ++m)
                        nmat[myk][e0 + m] = Cr[m] * __expf(-Rr[m] * tau) * W[m];
                }
            }
        }
        __syncthreads();

        // ---- reduce: wave w owns jj = w, w+8 ----
        for (int jj = w; jj <= jhi - j0; jj += NWAVES) {
            const int j = j0 + jj;
            if (!IS_TYPE && j == ne) continue;      // handled via nmat
            const int ie = (j < ne) ? evl[j] : SL;
            float p = 0.f;
            #pragma unroll
            for (int m2 = 0; m2 < NWAVES; ++m2) {
                const int src = lane + 64 * m2;
                if (src < NACT) p += qmat[jj][src];
            }
            if (IS_TYPE) {
                if (j < ne) p += trE * (aE + bmat[cats_sh[ie - 1] * ED + lane]);
                else        p += trE * aE;
            }
            const float r = waveReduceSum(p);
            if (lane == 0) {
                if (IS_TYPE) {
                    if (j < ne) ws[WS_M + b * SL + ie] = r;
                    else        ws[WS_IT + b * NTY + tgt] = r;
                } else {
                    ws[WS_N + b * SL + ie] = r;
                }
            }
        }
        __syncthreads();
    }

    // ---- cat horizon n-vector (only the last_cat block writes) ----
    if (!IS_TYPE && tgt == lastc && w == 0) {
        float nacc = 0.f;
        #pragma unroll
        for (int k = 0; k < NCA; ++k) nacc += nmat[k][lane];
        ws[WS_NT + b * ED + lane] = nacc;
    }
}

__global__ __launch_bounds__(NTHREADS) void hawkes_main(
        const float* __restrict__ times,
        const int*   __restrict__ types,
        const int*   __restrict__ cats,
        const int*   __restrict__ Tp,
        const float* __restrict__ type_emb,
        const float* __restrict__ cat_emb,
        const float* __restrict__ amat,
        const float* __restrict__ bmat,
        const float* __restrict__ A,
        const float* __restrict__ P,
        const float* __restrict__ Bm,
        const float* __restrict__ Q,
        float* __restrict__ ws) {
    const int blk = blockIdx.x;
    const int tid = threadIdx.x;

    __shared__ float times_sh[SL + 1];
    __shared__ int   types_sh[SL];
    __shared__ int   cats_sh[SL];
    __shared__ int   evl[SL];
    __shared__ int   evcnt;
    __shared__ float qmat[JTILE][NTHREADS];
    __shared__ float nmat[NCA][ED];

    const float Tf = (float)Tp[0];

    if (blk < TYPE_BLOCKS) {
        const int b = blk / NTY, tgt = blk % NTY;
        run_channel<true, NTY, 8>(b, tgt, tid, times, types, cats, Tf,
                                  type_emb, cat_emb, amat, bmat, A, P, ws,
                                  times_sh, types_sh, cats_sh, evl, &evcnt,
                                  qmat, nmat);
    } else {
        const int cb = blk - TYPE_BLOCKS;
        const int b = cb / NCA, tgt = cb % NCA;
        run_channel<false, NCA, 4>(b, tgt, tid, times, types, cats, Tf,
                                   type_emb, cat_emb, amat, bmat, Bm, Q, ws,
                                   times_sh, types_sh, cats_sh, evl, &evcnt,
                                   qmat, nmat);
    }
}

__global__ __launch_bounds__(256) void hawkes_final(
        const float* __restrict__ times,
        const int*   __restrict__ types,
        const int*   __restrict__ cats,
        const int*   __restrict__ Tp,
        const float* __restrict__ type_emb,
        const float* __restrict__ amat,
        const float* __restrict__ bmat,
        const float* __restrict__ ws,
        float* __restrict__ out) {
    const int tid  = threadIdx.x;
    const int lane = tid & 63;
    const int w    = tid >> 6;          // wave w also owns batch w

    __shared__ float tsl[4][ED];
    __shared__ float wred[4], i0red[4], intb[4];

    const float Tf = (float)Tp[0];

    // ---- log-likelihood over events i>=1 (thread tid -> i=tid+1, all batches) ----
    float llp = 0.f;
    const int i = tid + 1;
    if (i < SL) {
        #pragma unroll
        for (int bb = 0; bb < NB; ++bb) {
            const float lam = ws[WS_M + bb * SL + i] + ws[WS_N + bb * SL + i];
            llp += logf(lam + 1e-16f) + lam;
        }
    }

    // ---- empty-history lambda_0 for batch w ----
    const int t0 = types[w * SL];
    const float v0 = softplusf(type_emb[t0 * ED + lane] * amat[t0 * ED + lane]);

    // ---- TS[e] = sum_t te[t,e] and I0, t split by wave ----
    float tsp = 0.f, i0p = 0.f;
    for (int t = w; t < NTY; t += 4) {
        const float tv = type_emb[t * ED + lane];
        tsp += tv;
        i0p += softplusf(tv * amat[t * ED + lane]);
    }
    tsl[w][lane] = tsp;

    const float lam0 = waveReduceSum(v0);
    const float wll  = waveReduceSum(llp);
    const float wi0  = waveReduceSum(i0p);
    if (lane == 0) {
        wred[w]  = wll + logf(lam0 + 1e-16f) + lam0;
        i0red[w] = wi0;
    }
    __syncthreads();

    // ---- horizon integral for batch w ----
    const float TS_l = tsl[0][lane] + tsl[1][lane] + tsl[2][lane] + tsl[3][lane];
    const int   lc   = cats[w * SL + SL - 1];
    const float bbv  = bmat[lc * ED + lane] + ws[WS_NT + w * ED + lane];
    const float its  = (lane < NTY) ? ws[WS_IT + w * NTY + lane] : 0.f;
    const float ip   = waveReduceSum(its + bbv * TS_l);
    if (lane == 0) intb[w] = ip * (Tf - times[w * SL + SL - 1]);
    __syncthreads();

    if (tid == 0) {
        const float ll = wred[0] + wred[1] + wred[2] + wred[3];
        const float I0 = i0red[0] + i0red[1] + i0red[2] + i0red[3];
        const float t0s = times[0] + times[SL] + times[2 * SL] + times[3 * SL];
        const float tot = intb[0] + intb[1] + intb[2] + intb[3] + I0 * t0s;
        out[0] = -(ll - tot);
    }
}

extern "C" void kernel_launch(void* const* d_in, const int* in_sizes, int n_in,
                              void* d_out, int out_size, void* d_ws, size_t ws_size,
                              hipStream_t stream) {
    const float* times    = (const float*)d_in[0];
    const int*   types    = (const int*)  d_in[1];
    const int*   cats     = (const int*)  d_in[2];
    const int*   Tp       = (const int*)  d_in[3];
    const float* type_emb = (const float*)d_in[4];
    const float* cat_emb  = (const float*)d_in[5];
    const float* amat     = (const float*)d_in[6];
    const float* bmat     = (const float*)d_in[7];
    const float* A        = (const float*)d_in[8];
    const float* P        = (const float*)d_in[9];
    const float* Bm       = (const float*)d_in[10];
    const float* Q        = (const float*)d_in[11];
    float* out = (float*)d_out;
    float* ws  = (float*)d_ws;

    // No memset: every ws slot read by hawkes_final is written exactly once.
    hawkes_main<<<MAIN_BLOCKS, NTHREADS, 0, stream>>>(times, types, cats, Tp,
                                                      type_emb, cat_emb, amat, bmat,
                                                      A, P, Bm, Q, ws);
    hawkes_final<<<1, 256, 0, stream>>>(times, types, cats, Tp,
                                        type_emb, amat, bmat, ws, out);
}

// Round 3
// 109.313 us; speedup vs baseline: 1.3675x; 1.0976x over previous
//
#include <hip/hip_runtime.h>

#define NTY 50
#define NCA 20
#define ED  64
#define NB  4
#define SL  256

#define TYPE_BLOCKS (NB * NTY)   // 200: one per (batch, target type)
#define CAT_BLOCKS  (NB * NCA)   // 80:  one per (batch, target category)
#define MAIN_BLOCKS (TYPE_BLOCKS + CAT_BLOCKS)
#define NTHREADS 512
#define NWAVES   (NTHREADS / 64)
#define JTILE    16

// ws float layout — every slot has exactly ONE writer, no zero-init needed:
#define WS_M  0                        // [NB][SL] per-event type-channel partial
#define WS_N  (NB * SL)                // [NB][SL] per-event cat-channel partial
#define WS_IT (2 * NB * SL)            // [NB][NTY] horizon type partial
#define WS_NT (2 * NB * SL + NB * NTY) // [NB][ED] horizon cat n-vector

__device__ __forceinline__ float softplusf(float x) {
    return (x > 0.f) ? x + log1pf(__expf(-x)) : log1pf(__expf(x));
}

__device__ __forceinline__ float waveReduceSum(float v) {
    #pragma unroll
    for (int off = 32; off > 0; off >>= 1) v += __shfl_down(v, off, 64);
    return v;
}

struct SharedBuf {
    float times_sh[SL + 1];
    int   types_sh[SL];
    int   cats_sh[SL];
    int   kcnt[NTY];
    int   csr_off[NTY + 1];
    int   csr_pos[SL];
    int   evl[SL];
    int   evcnt;
    float trA;
    float trB[NCA];
    float qmat[JTILE][NTHREADS];
    float nmat[NCA][ED];
    float temb[NTY][ED];
};

// Thread owns (k, EPT e-values); W[e] = sum_{matched s<i} exp(R[e]*t_s) in VGPRs.
// CSR index per key k means the event loop touches ONLY matched sources
// (~N/NK of them), not all 256 — the serial LDS chain shrinks 10-23x.
template <bool IS_TYPE, int NK, int EPT>
__device__ __forceinline__ void run_channel(
        int b, int tgt, int tid,
        const float* __restrict__ times, const int* __restrict__ types,
        const int* __restrict__ cats, float Tf,
        const float* __restrict__ type_emb, const float* __restrict__ cat_emb,
        const float* __restrict__ amat, const float* __restrict__ bmat,
        const float* __restrict__ Cmat, const float* __restrict__ Pmat,
        float* __restrict__ ws, SharedBuf& sh) {
    const int lane = tid & 63;
    const int w    = tid >> 6;
    constexpr int GPK  = ED / EPT;     // thread-groups per k
    constexpr int NACT = NK * GPK;     // active threads
    const int myk  = tid / GPK;
    const int e0   = (tid % GPK) * EPT;
    const bool active = tid < NACT;
    const int base = b * SL;

    // ---- per-thread coefficient registers (globals issued first, overlap staging) ----
    float Rr[EPT], Cr[EPT], W[EPT];
    if (active) {
        #pragma unroll
        for (int m = 0; m < EPT; ++m) {
            const int e = e0 + m;
            const float tr = IS_TYPE ? type_emb[tgt * ED + e] : cat_emb[tgt * ED + e];
            const float f  = IS_TYPE ? type_emb[myk * ED + e] : cat_emb[myk * ED + e];
            Cr[m] = tr * Cmat[(myk * NK + tgt) * ED + e] * f;
            Rr[m] = tr * Pmat[(myk * NK + tgt) * ED + e] * f;
            W[m]  = 0.f;
        }
    }
    float trE = 0.f, aE = 0.f;
    if (IS_TYPE) {
        trE = type_emb[tgt * ED + lane];
        aE  = amat[tgt * ED + lane];
    }

    // ---- stage sequences (+ all of type_emb for cat-channel queries) ----
    if (tid < SL) {
        sh.times_sh[tid] = times[base + tid];
        sh.types_sh[tid] = types[base + tid];
        sh.cats_sh[tid]  = cats[base + tid];
    }
    if (tid == 0) sh.times_sh[SL] = Tf;   // virtual horizon event
    if (!IS_TYPE) {
        for (int idx = tid; idx < NTY * ED; idx += NTHREADS)
            (&sh.temb[0][0])[idx] = type_emb[idx];
    }
    __syncthreads();

    const int* keys = IS_TYPE ? sh.types_sh : sh.cats_sh;

    // ---- CSR count (wave w owns k ≡ w mod 8); wave 7 also compacts events ----
    for (int k = w; k < NK; k += NWAVES) {
        int cnt = 0;
        #pragma unroll
        for (int c = 0; c < SL / 64; ++c)
            cnt += __popcll(__ballot(keys[lane + 64 * c] == k));
        if (lane == 0) sh.kcnt[k] = cnt;
    }
    if (w == NWAVES - 1) {
        int run = 0;
        #pragma unroll
        for (int c = 0; c < SL / 64; ++c) {
            const int p = lane + 64 * c;
            const bool pred = (p >= 1) && (IS_TYPE ? (sh.types_sh[p] == tgt)
                                                   : (sh.cats_sh[p - 1] == tgt));
            const unsigned long long mk = __ballot(pred);
            if (pred) sh.evl[run + __popcll(mk & ((1ull << lane) - 1ull))] = p;
            run += __popcll(mk);
        }
        if (lane == 0) sh.evcnt = run;
    }
    __syncthreads();

    // ---- offsets scan (wave 0); epilogue scalars trA/trB[c] (other waves) ----
    if (w == 0) {
        int v = (lane < NK) ? sh.kcnt[lane] : 0;
        #pragma unroll
        for (int off = 1; off < 64; off <<= 1) {
            const int u = __shfl_up(v, off, 64);
            if (lane >= off) v += u;
        }
        if (lane < NK) sh.csr_off[lane + 1] = v;
        if (lane == 0) sh.csr_off[0] = 0;
    }
    if (IS_TYPE) {
        if (w == 1) {
            const float r = waveReduceSum(trE * aE);
            if (lane == 0) sh.trA = r;
        }
        for (int c = w; c < NCA; c += NWAVES) {
            const float r = waveReduceSum(trE * bmat[c * ED + lane]);
            if (lane == 0) sh.trB[c] = r;
        }
    }
    __syncthreads();

    // ---- CSR rank-write (position-sorted within each k by chunk order) ----
    for (int k = w; k < NK; k += NWAVES) {
        int bp = sh.csr_off[k];
        #pragma unroll
        for (int c = 0; c < SL / 64; ++c) {
            const int p = lane + 64 * c;
            const bool pred = (keys[p] == k);
            const unsigned long long mk = __ballot(pred);
            if (pred) sh.csr_pos[bp + __popcll(mk & ((1ull << lane) - 1ull))] = p;
            bp += __popcll(mk);
        }
    }
    __syncthreads();

    const int ne    = sh.evcnt;
    const int lastc = sh.cats_sh[SL - 1];
    int       m     = active ? sh.csr_off[myk] : 0;
    const int mend  = active ? sh.csr_off[myk + 1] : 0;

    for (int j0 = 0; j0 <= ne; j0 += JTILE) {
        const int jhi = min(j0 + JTILE - 1, ne);

        // ---- emit: per-thread matched-source advance + query, no barriers ----
        if (active) {
            for (int j = j0; j <= jhi; ++j) {
                const int ie = (j < ne) ? sh.evl[j] : SL;
                while (m < mend) {
                    const int pos = sh.csr_pos[m];
                    if (pos >= ie) break;
                    const float ts = sh.times_sh[pos];
                    #pragma unroll
                    for (int mm = 0; mm < EPT; ++mm) W[mm] += __expf(Rr[mm] * ts);
                    ++m;
                }
                const float tau = sh.times_sh[ie];
                if (IS_TYPE || j < ne) {
                    float q = 0.f;
                    #pragma unroll
                    for (int mm = 0; mm < EPT; ++mm) {
                        float v = Cr[mm] * __expf(-Rr[mm] * tau) * W[mm];
                        if (!IS_TYPE) v *= sh.temb[sh.types_sh[ie]][e0 + mm];
                        q += v;
                    }
                    sh.qmat[j - j0][tid] = q;
                } else {
                    // cat virtual event: keep per-e vector for n_T
                    #pragma unroll
                    for (int mm = 0; mm < EPT; ++mm)
                        sh.nmat[myk][e0 + mm] = Cr[mm] * __expf(-Rr[mm] * tau) * W[mm];
                }
            }
        }
        __syncthreads();

        // ---- reduce: wave w owns jj = w, w+8; pure LDS + shuffle ----
        for (int jj = w; jj <= jhi - j0; jj += NWAVES) {
            const int j = j0 + jj;
            if (!IS_TYPE && j == ne) continue;      // handled via nmat
            const int ie = (j < ne) ? sh.evl[j] : SL;
            float p = 0.f;
            #pragma unroll
            for (int m2 = 0; m2 < NWAVES; ++m2) {
                const int src = lane + 64 * m2;
                if (src < NACT) p += sh.qmat[jj][src];
            }
            const float r = waveReduceSum(p);
            if (lane == 0) {
                if (IS_TYPE) {
                    if (j < ne) ws[WS_M + b * SL + ie] = r + sh.trA + sh.trB[sh.cats_sh[ie - 1]];
                    else        ws[WS_IT + b * NTY + tgt] = r + sh.trA;
                } else {
                    ws[WS_N + b * SL + ie] = r;
                }
            }
        }
        __syncthreads();
    }

    // ---- cat horizon n-vector (only the last_cat block writes) ----
    if (!IS_TYPE && tgt == lastc && w == 0) {
        float nacc = 0.f;
        #pragma unroll
        for (int k = 0; k < NCA; ++k) nacc += sh.nmat[k][lane];
        ws[WS_NT + b * ED + lane] = nacc;
    }
}

__global__ __launch_bounds__(NTHREADS) void hawkes_main(
        const float* __restrict__ times,
        const int*   __restrict__ types,
        const int*   __restrict__ cats,
        const int*   __restrict__ Tp,
        const float* __restrict__ type_emb,
        const float* __restrict__ cat_emb,
        const float* __restrict__ amat,
        const float* __restrict__ bmat,
        const float* __restrict__ A,
        const float* __restrict__ P,
        const float* __restrict__ Bm,
        const float* __restrict__ Q,
        float* __restrict__ ws) {
    const int blk = blockIdx.x;
    const int tid = threadIdx.x;
    __shared__ SharedBuf sh;

    const float Tf = (float)Tp[0];

    if (blk < TYPE_BLOCKS) {
        const int b = blk / NTY, tgt = blk % NTY;
        run_channel<true, NTY, 8>(b, tgt, tid, times, types, cats, Tf,
                                  type_emb, cat_emb, amat, bmat, A, P, ws, sh);
    } else {
        const int cb = blk - TYPE_BLOCKS;
        const int b = cb / NCA, tgt = cb % NCA;
        run_channel<false, NCA, 4>(b, tgt, tid, times, types, cats, Tf,
                                   type_emb, cat_emb, amat, bmat, Bm, Q, ws, sh);
    }
}

__global__ __launch_bounds__(256) void hawkes_final(
        const float* __restrict__ times,
        const int*   __restrict__ types,
        const int*   __restrict__ cats,
        const int*   __restrict__ Tp,
        const float* __restrict__ type_emb,
        const float* __restrict__ amat,
        const float* __restrict__ bmat,
        const float* __restrict__ ws,
        float* __restrict__ out) {
    const int tid  = threadIdx.x;
    const int lane = tid & 63;
    const int w    = tid >> 6;          // wave w also owns batch w

    __shared__ float tsl[4][ED];
    __shared__ float wred[4], i0red[4], intb[4];

    const float Tf = (float)Tp[0];

    // ---- log-likelihood over events i>=1 (thread tid -> i=tid+1, all batches) ----
    float llp = 0.f;
    const int i = tid + 1;
    if (i < SL) {
        #pragma unroll
        for (int bb = 0; bb < NB; ++bb) {
            const float lam = ws[WS_M + bb * SL + i] + ws[WS_N + bb * SL + i];
            llp += logf(lam + 1e-16f) + lam;
        }
    }

    // ---- empty-history lambda_0 for batch w ----
    const int t0 = types[w * SL];
    const float v0 = softplusf(type_emb[t0 * ED + lane] * amat[t0 * ED + lane]);

    // ---- TS[e] = sum_t te[t,e] and I0, t split by wave ----
    float tsp = 0.f, i0p = 0.f;
    for (int t = w; t < NTY; t += 4) {
        const float tv = type_emb[t * ED + lane];
        tsp += tv;
        i0p += softplusf(tv * amat[t * ED + lane]);
    }
    tsl[w][lane] = tsp;

    const float lam0 = waveReduceSum(v0);
    const float wll  = waveReduceSum(llp);
    const float wi0  = waveReduceSum(i0p);
    if (lane == 0) {
        wred[w]  = wll + logf(lam0 + 1e-16f) + lam0;
        i0red[w] = wi0;
    }
    __syncthreads();

    // ---- horizon integral for batch w ----
    const float TS_l = tsl[0][lane] + tsl[1][lane] + tsl[2][lane] + tsl[3][lane];
    const int   lc   = cats[w * SL + SL - 1];
    const float bbv  = bmat[lc * ED + lane] + ws[WS_NT + w * ED + lane];
    const float its  = (lane < NTY) ? ws[WS_IT + w * NTY + lane] : 0.f;
    const float ip   = waveReduceSum(its + bbv * TS_l);
    if (lane == 0) intb[w] = ip * (Tf - times[w * SL + SL - 1]);
    __syncthreads();

    if (tid == 0) {
        const float ll = wred[0] + wred[1] + wred[2] + wred[3];
        const float I0 = i0red[0] + i0red[1] + i0red[2] + i0red[3];
        const float t0s = times[0] + times[SL] + times[2 * SL] + times[3 * SL];
        const float tot = intb[0] + intb[1] + intb[2] + intb[3] + I0 * t0s;
        out[0] = -(ll - tot);
    }
}

extern "C" void kernel_launch(void* const* d_in, const int* in_sizes, int n_in,
                              void* d_out, int out_size, void* d_ws, size_t ws_size,
                              hipStream_t stream) {
    const float* times    = (const float*)d_in[0];
    const int*   types    = (const int*)  d_in[1];
    const int*   cats     = (const int*)  d_in[2];
    const int*   Tp       = (const int*)  d_in[3];
    const float* type_emb = (const float*)d_in[4];
    const float* cat_emb  = (const float*)d_in[5];
    const float* amat     = (const float*)d_in[6];
    const float* bmat     = (const float*)d_in[7];
    const float* A        = (const float*)d_in[8];
    const float* P        = (const float*)d_in[9];
    const float* Bm       = (const float*)d_in[10];
    const float* Q        = (const float*)d_in[11];
    float* out = (float*)d_out;
    float* ws  = (float*)d_ws;

    // No memset: every ws slot read by hawkes_final is written exactly once.
    hawkes_main<<<MAIN_BLOCKS, NTHREADS, 0, stream>>>(times, types, cats, Tp,
                                                      type_emb, cat_emb, amat, bmat,
                                                      A, P, Bm, Q, ws);
    hawkes_final<<<1, 256, 0, stream>>>(times, types, cats, Tp,
                                        type_emb, amat, bmat, ws, out);
}